// Round 1
// baseline (10608.988 us; speedup 1.0000x reference)
//
#include <hip/hip_runtime.h>

#define DEVINL __device__ __forceinline__

DEVINL float sigm(float x) { return 1.0f / (1.0f + __expf(-x)); }

DEVINL float wsum(float v) {
#pragma unroll
  for (int off = 32; off > 0; off >>= 1) v += __shfl_xor(v, off, 64);
  return v;
}

DEVINL float dot4(float4 a, float4 w) {
  return a.x * w.x + a.y * w.y + a.z * w.z + a.w * w.w;
}

// ---------------- embedding: out[s][b][:] = W[idx[b][s]] ----------------
__global__ void embed_tm(const int* __restrict__ idx, const float* __restrict__ W,
                         float* __restrict__ out, int S, int B, int E) {
  long i = (long)blockIdx.x * blockDim.x + threadIdx.x;
  if (i >= (long)S * B * E) return;
  int e = (int)(i % E);
  int sb = (int)(i / E);
  int b = sb % B, s = sb / B;
  out[i] = W[(long)idx[b * S + s] * E + e];
}

// ---------------- fp32 GEMM: C = A @ W^T + b1 + b2, 128x128 tile ----------------
// A[M,K], W[N,K] row-major. If remapT>0: logical row m=(t*remapB+b) stored at row b*remapT+t.
// 256 threads; micro-tile 16m x 4n per thread (5 LDS b128 reads per 64 FMA -> VALU-bound).
__global__ __launch_bounds__(256) void gemm_nt(
    const float* __restrict__ A, const float* __restrict__ W,
    const float* __restrict__ b1, const float* __restrict__ b2,
    float* __restrict__ C, int M, int N, int K, int remapB, int remapT) {
  __shared__ __align__(16) float As[16][132];
  __shared__ __align__(16) float Ws[16][132];
  const int m0 = blockIdx.y * 128;
  const int n0 = blockIdx.x * 128;
  const int tid = threadIdx.x;
  const int tx = tid & 31;   // n group: 32 x 4 cols
  const int ty = tid >> 5;   // m group: 8 x 16 rows
  float acc[16][4] = {};
  const int lk = tid & 15;
  const int lr0 = tid >> 4;
  for (int k0 = 0; k0 < K; k0 += 16) {
#pragma unroll
    for (int p = 0; p < 8; p++) {
      int r = lr0 + p * 16;
      int gm = m0 + r;
      As[lk][r] = (gm < M) ? A[(size_t)gm * K + k0 + lk] : 0.0f;
      int gn = n0 + r;
      Ws[lk][r] = (gn < N) ? W[(size_t)gn * K + k0 + lk] : 0.0f;
    }
    __syncthreads();
#pragma unroll
    for (int kk = 0; kk < 16; kk++) {
      float4 w4 = *(const float4*)&Ws[kk][tx * 4];
      const float wv[4] = {w4.x, w4.y, w4.z, w4.w};
#pragma unroll
      for (int q = 0; q < 4; q++) {
        float4 a4 = *(const float4*)&As[kk][ty * 16 + q * 4];
        const float av[4] = {a4.x, a4.y, a4.z, a4.w};
#pragma unroll
        for (int c = 0; c < 4; c++)
#pragma unroll
          for (int j = 0; j < 4; j++) acc[q * 4 + c][j] += av[c] * wv[j];
      }
    }
    __syncthreads();
  }
  float bn[4];
#pragma unroll
  for (int j = 0; j < 4; j++) {
    int gn = n0 + tx * 4 + j;
    bn[j] = 0.0f;
    if (gn < N) {
      if (b1) bn[j] += b1[gn];
      if (b2) bn[j] += b2[gn];
    }
  }
#pragma unroll
  for (int i = 0; i < 16; i++) {
    int gm = m0 + ty * 16 + i;
    if (gm >= M) continue;
    size_t row;
    if (remapT > 0) {
      int t = gm / remapB, b = gm % remapB;
      row = (size_t)b * remapT + t;
    } else {
      row = (size_t)gm;
    }
    int gn0 = n0 + tx * 4;
    if (gn0 + 3 < N) {
      float4 v = make_float4(acc[i][0] + bn[0], acc[i][1] + bn[1],
                             acc[i][2] + bn[2], acc[i][3] + bn[3]);
      *(float4*)&C[row * (size_t)N + gn0] = v;
    } else {
#pragma unroll
      for (int j = 0; j < 4; j++) {
        int gn = gn0 + j;
        if (gn < N) C[row * (size_t)N + gn] = acc[i][j] + bn[j];
      }
    }
  }
}

// ---------------- encoder recurrent step, both directions fused ----------------
// wave per (dir, j, batch-group-of-4); 4 waves of a block share the same weight rows.
// xg layout: [S*B][4096] (fwd gates 0..2047, bwd gates 2048..4095).
__global__ __launch_bounds__(256) void enc_step(
    const float* __restrict__ xg,
    const float* __restrict__ Whh_f, const float* __restrict__ Whh_b,
    const float* __restrict__ h_in, const float* __restrict__ c_in,
    float* __restrict__ h_out, float* __restrict__ c_out,
    float* __restrict__ x_out,
    float* __restrict__ hfin, float* __restrict__ cfin,
    int k, int S, int last) {
  int gid = (blockIdx.x * blockDim.x + threadIdx.x) >> 6;
  int lane = threadIdx.x & 63;
  int dir = gid >> 11;   // 2048 waves per dir (512 j * 4 bg)
  int rem = gid & 2047;
  int j = rem >> 2;
  int bg = rem & 3;
  const float* Whh = dir ? Whh_b : Whh_f;
  int t = dir ? (S - 1 - k) : k;
  const float* w0 = Whh + (size_t)j * 512;
  const float* w1 = w0 + (size_t)512 * 512;
  const float* w2 = w0 + (size_t)1024 * 512;
  const float* w3 = w0 + (size_t)1536 * 512;
  const float* hb = h_in + ((size_t)dir * 16 + bg * 4) * 512;
  float acc[4][4] = {};  // [gate][bb]
  for (int kk = lane * 4; kk < 512; kk += 256) {
    float4 wv0 = *(const float4*)(w0 + kk);
    float4 wv1 = *(const float4*)(w1 + kk);
    float4 wv2 = *(const float4*)(w2 + kk);
    float4 wv3 = *(const float4*)(w3 + kk);
#pragma unroll
    for (int bb = 0; bb < 4; bb++) {
      float4 av = *(const float4*)(hb + (size_t)bb * 512 + kk);
      acc[0][bb] += dot4(av, wv0);
      acc[1][bb] += dot4(av, wv1);
      acc[2][bb] += dot4(av, wv2);
      acc[3][bb] += dot4(av, wv3);
    }
  }
#pragma unroll
  for (int g = 0; g < 4; g++)
#pragma unroll
    for (int bb = 0; bb < 4; bb++) acc[g][bb] = wsum(acc[g][bb]);
  if (lane == 0) {
#pragma unroll
    for (int bb = 0; bb < 4; bb++) {
      int b = bg * 4 + bb;
      const float* xr = xg + ((size_t)t * 16 + b) * 4096 + dir * 2048 + j;
      float gi = acc[0][bb] + xr[0];
      float gf = acc[1][bb] + xr[512];
      float gg = acc[2][bb] + xr[1024];
      float go = acc[3][bb] + xr[1536];
      int si = (dir * 16 + b) * 512 + j;
      float c = sigm(gf) * c_in[si] + sigm(gi) * tanhf(gg);
      float hv = sigm(go) * tanhf(c);
      h_out[si] = hv;
      c_out[si] = c;
      x_out[((size_t)t * 16 + b) * 1024 + dir * 512 + j] = hv;
      if (last) {
        hfin[b * 1024 + dir * 512 + j] = hv;
        cfin[b * 1024 + dir * 512 + j] = c;
      }
    }
  }
}

// ---------------- decoder LSTM layer: up to 3 (A,W) pairs + biases + cell ----------------
// wave per (j, batch-group-of-4): each weight-row read serves 4 batches;
// 4 waves of a block share the same rows (j-major gid mapping).
DEVINL void pair_acc4(const float* __restrict__ A, const float* __restrict__ W,
                      int ldw, int K, int b0, int j, int N, int lane, float acc[4][4]) {
  const float* w0 = W + (size_t)j * ldw;
  const float* w1 = W + (size_t)(N + j) * ldw;
  const float* w2 = W + (size_t)(2 * N + j) * ldw;
  const float* w3 = W + (size_t)(3 * N + j) * ldw;
  const float* a0 = A + (size_t)b0 * K;
  for (int k = lane * 4; k < K; k += 256) {
    float4 wv0 = *(const float4*)(w0 + k);
    float4 wv1 = *(const float4*)(w1 + k);
    float4 wv2 = *(const float4*)(w2 + k);
    float4 wv3 = *(const float4*)(w3 + k);
#pragma unroll
    for (int bb = 0; bb < 4; bb++) {
      float4 av = *(const float4*)(a0 + (size_t)bb * K + k);
      acc[0][bb] += dot4(av, wv0);
      acc[1][bb] += dot4(av, wv1);
      acc[2][bb] += dot4(av, wv2);
      acc[3][bb] += dot4(av, wv3);
    }
  }
}

__global__ __launch_bounds__(256) void lstm_gates_cell(
    const float* __restrict__ A1, const float* __restrict__ W1, int ldw1, int K1,
    const float* __restrict__ A2, const float* __restrict__ W2, int ldw2, int K2,
    const float* __restrict__ A3, const float* __restrict__ W3, int ldw3, int K3,
    const float* __restrict__ b1, const float* __restrict__ b2,
    const float* __restrict__ c_in, float* __restrict__ h_out, float* __restrict__ c_out,
    int N, int Bx) {
  int gid = (blockIdx.x * blockDim.x + threadIdx.x) >> 6;
  int lane = threadIdx.x & 63;
  int j = gid >> 2;
  int bg = gid & 3;
  if (j >= N) return;
  int b0 = bg * 4;
  float acc[4][4] = {};
  pair_acc4(A1, W1, ldw1, K1, b0, j, N, lane, acc);
  if (A2) pair_acc4(A2, W2, ldw2, K2, b0, j, N, lane, acc);
  if (A3) pair_acc4(A3, W3, ldw3, K3, b0, j, N, lane, acc);
#pragma unroll
  for (int g = 0; g < 4; g++)
#pragma unroll
    for (int bb = 0; bb < 4; bb++) acc[g][bb] = wsum(acc[g][bb]);
  if (lane == 0) {
    float bi_ = (b1 ? b1[j] : 0.f) + (b2 ? b2[j] : 0.f);
    float bf_ = (b1 ? b1[N + j] : 0.f) + (b2 ? b2[N + j] : 0.f);
    float bg_ = (b1 ? b1[2 * N + j] : 0.f) + (b2 ? b2[2 * N + j] : 0.f);
    float bo_ = (b1 ? b1[3 * N + j] : 0.f) + (b2 ? b2[3 * N + j] : 0.f);
#pragma unroll
    for (int bb = 0; bb < 4; bb++) {
      int b = b0 + bb;
      float gi = acc[0][bb] + bi_, gf = acc[1][bb] + bf_;
      float gg = acc[2][bb] + bg_, go = acc[3][bb] + bo_;
      int si = b * N + j;
      float c = sigm(gf) * c_in[si] + sigm(gi) * tanhf(gg);
      float hv = sigm(go) * tanhf(c);
      h_out[si] = hv;
      c_out[si] = c;
    }
  }
  (void)Bx;
}

// ---------------- skinny matmul: out = act(A1@W1^T + A2@W2^T + bias) ----------------
// wave per (n, batch-group-of-4), weight row read once per 4 batches.
__global__ __launch_bounds__(256) void skinny_nt(
    const float* __restrict__ A1, const float* __restrict__ W1, int ldw1, int K1,
    const float* __restrict__ A2, const float* __restrict__ W2, int ldw2, int K2,
    const float* __restrict__ bias, float* __restrict__ out1, float* __restrict__ out2,
    int N, int Bx, int act) {
  int gid = (blockIdx.x * blockDim.x + threadIdx.x) >> 6;
  int lane = threadIdx.x & 63;
  int n = gid >> 2;
  int bg = gid & 3;
  if (n >= N) return;
  int b0 = bg * 4;
  float acc[4] = {0.f, 0.f, 0.f, 0.f};
  {
    const float* w = W1 + (size_t)n * ldw1;
    for (int k = lane * 4; k < K1; k += 256) {
      float4 wv = *(const float4*)(w + k);
#pragma unroll
      for (int bb = 0; bb < 4; bb++) {
        float4 av = *(const float4*)(A1 + (size_t)(b0 + bb) * K1 + k);
        acc[bb] += dot4(av, wv);
      }
    }
  }
  if (A2) {
    const float* w = W2 + (size_t)n * ldw2;
    for (int k = lane * 4; k < K2; k += 256) {
      float4 wv = *(const float4*)(w + k);
#pragma unroll
      for (int bb = 0; bb < 4; bb++) {
        float4 av = *(const float4*)(A2 + (size_t)(b0 + bb) * K2 + k);
        acc[bb] += dot4(av, wv);
      }
    }
  }
#pragma unroll
  for (int bb = 0; bb < 4; bb++) acc[bb] = wsum(acc[bb]);
  if (lane == 0) {
    float bsv = bias ? bias[n] : 0.f;
#pragma unroll
    for (int bb = 0; bb < 4; bb++) {
      float v = acc[bb] + bsv;
      if (act == 1) v = tanhf(v);
      out1[(b0 + bb) * N + n] = v;
      if (out2) out2[(b0 + bb) * N + n] = v;
    }
  }
  (void)Bx;
}

// ---------------- attention: scores -> softmax -> context, one block per batch ----------------
__global__ __launch_bounds__(256) void attn_ctx(const float* __restrict__ q,
                                                const float* __restrict__ hsrc,
                                                float* __restrict__ ctx, int S, int B) {
  int b = blockIdx.x;
  __shared__ float sc[64];
  __shared__ float qs[1024];
  for (int i = threadIdx.x; i < 1024; i += 256) qs[i] = q[b * 1024 + i];
  __syncthreads();
  int wave = threadIdx.x >> 6, lane = threadIdx.x & 63;
  for (int s = wave; s < S; s += 4) {
    const float* hr = hsrc + ((size_t)s * B + b) * 1024;
    float acc = 0.f;
    for (int k = lane * 4; k < 1024; k += 256) {
      float4 hv = *(const float4*)(hr + k);
      acc += hv.x * qs[k] + hv.y * qs[k + 1] + hv.z * qs[k + 2] + hv.w * qs[k + 3];
    }
    acc = wsum(acc);
    if (lane == 0) sc[s] = acc;
  }
  __syncthreads();
  if (threadIdx.x == 0) {
    float m = -1e30f;
    for (int s = 0; s < S; s++) m = fmaxf(m, sc[s]);
    float sum = 0.f;
    for (int s = 0; s < S; s++) { float e = __expf(sc[s] - m); sc[s] = e; sum += e; }
    float inv = 1.0f / sum;
    for (int s = 0; s < S; s++) sc[s] *= inv;
  }
  __syncthreads();
  for (int h = threadIdx.x; h < 1024; h += 256) {
    float acc = 0.f;
    for (int s = 0; s < S; s++) acc += sc[s] * hsrc[((size_t)s * B + b) * 1024 + h];
    ctx[b * 1024 + h] = acc;
  }
}

// ---------------- in-place row log-softmax ----------------
__global__ __launch_bounds__(256) void log_softmax_rows(float* __restrict__ p_, int V) {
  float* p = p_ + (size_t)blockIdx.x * V;
  __shared__ float red[4];
  __shared__ float bval;
  int lane = threadIdx.x & 63, wv = threadIdx.x >> 6;
  float m = -1e30f;
  for (int v = threadIdx.x; v < V; v += 256) m = fmaxf(m, p[v]);
#pragma unroll
  for (int off = 32; off > 0; off >>= 1) m = fmaxf(m, __shfl_xor(m, off, 64));
  if (lane == 0) red[wv] = m;
  __syncthreads();
  if (threadIdx.x == 0) bval = fmaxf(fmaxf(red[0], red[1]), fmaxf(red[2], red[3]));
  __syncthreads();
  m = bval;
  float s = 0.f;
  for (int v = threadIdx.x; v < V; v += 256) s += __expf(p[v] - m);
  s = wsum(s);
  if (lane == 0) red[wv] = s;
  __syncthreads();
  if (threadIdx.x == 0) bval = logf(red[0] + red[1] + red[2] + red[3]) + m;
  __syncthreads();
  float lz = bval;
  for (int v = threadIdx.x; v < V; v += 256) p[v] -= lz;
}

extern "C" void kernel_launch(void* const* d_in, const int* in_sizes, int n_in,
                              void* d_out, int out_size, void* d_ws, size_t ws_size,
                              hipStream_t stream) {
  const int L_ = 4, H_ = 1024, E_ = 1024, B_ = 16, S_ = 50, T_ = 50, V_ = 32000;
  const int* src = (const int*)d_in[0];
  const int* tgt = (const int*)d_in[1];
  const float* emb_src_W = (const float*)d_in[2];
  const float* emb_dec_W = (const float*)d_in[3];
  const float* enc_Wih = (const float*)d_in[4];
  const float* enc_Whh = (const float*)d_in[5];
  const float* enc_bih = (const float*)d_in[6];
  const float* enc_bhh = (const float*)d_in[7];
  const float* dec0_Wih = (const float*)d_in[8];
  const float* dec0_Whh = (const float*)d_in[9];
  const float* dec0_bih = (const float*)d_in[10];
  const float* dec0_bhh = (const float*)d_in[11];
  const float* dec_Wih = (const float*)d_in[12];
  const float* dec_Whh = (const float*)d_in[13];
  const float* dec_bih = (const float*)d_in[14];
  const float* dec_bhh = (const float*)d_in[15];
  const float* W_attn = (const float*)d_in[16];
  const float* W_concat = (const float*)d_in[17];
  const float* b_concat = (const float*)d_in[18];
  const float* W_out = (const float*)d_in[19];
  const float* b_out = (const float*)d_in[20];
  float* out = (float*)d_out;

  // ---- workspace layout (floats) ----
  float* ws = (float*)d_ws;
  float* x_a = ws;                     // S*B*H = 819200
  float* x_b = x_a + 819200;           // 819200
  float* xg = x_b + 819200;            // S*B*4096 = 3276800 (fused fwd+bwd gates)
  float* hstate = xg + 3276800;        // 2 parity * 2 dir * 16 * 512 = 32768
  float* cstate = hstate + 32768;      // 32768
  float* h_dec = cstate + 32768;       // 2 parity * 4*16*1024 = 131072
  float* c_dec = h_dec + 131072;       // 131072
  float* h_til = c_dec + 131072;       // 16384
  float* q_buf = h_til + 16384;        // 16384
  float* ctxb = q_buf + 16384;         // 16384
  // decoder-phase reuse of encoder scratch (xg is free after encoder):
  float* emb_t = xg;                   // T*B*E = 819200
  float* hts = xg + 819200;            // T*B*H = 819200 (h_tilde_seq)

  // ================= Encoder =================
  embed_tm<<<3200, 256, 0, stream>>>(src, emb_src_W, x_a, S_, B_, E_);

  for (int l = 0; l < L_; l++) {
    const float* xin = (l % 2 == 0) ? x_a : x_b;
    float* xout = (l % 2 == 0) ? x_b : x_a;
    hipMemsetAsync(hstate, 0, 16384 * sizeof(float), stream);
    hipMemsetAsync(cstate, 0, 16384 * sizeof(float), stream);
    // fused both-direction input projection: W rows [dir*2048 + gate*512 + j]
    dim3 gg(4096 / 128, (800 + 127) / 128);
    gemm_nt<<<gg, 256, 0, stream>>>(
        xin, enc_Wih + (size_t)l * 4096 * 1024,
        enc_bih + l * 4096, enc_bhh + l * 4096,
        xg, 800, 4096, 1024, 0, 0);
    for (int k = 0; k < S_; k++) {
      enc_step<<<1024, 256, 0, stream>>>(
          xg,
          enc_Whh + (size_t)(l * 2 + 0) * 2048 * 512, enc_Whh + (size_t)(l * 2 + 1) * 2048 * 512,
          hstate + (k & 1) * 16384, cstate + (k & 1) * 16384,
          hstate + ((k + 1) & 1) * 16384, cstate + ((k + 1) & 1) * 16384,
          xout,
          h_dec + l * 16384, c_dec + l * 16384,
          k, S_, (k == S_ - 1) ? 1 : 0);
    }
  }
  const float* hsrc = x_a;  // layer 3 output (time-major [S,B,H])

  // ================= Decoder =================
  embed_tm<<<3200, 256, 0, stream>>>(tgt, emb_dec_W, emb_t, T_, B_, E_);
  hipMemsetAsync(h_til, 0, 16384 * sizeof(float), stream);

  for (int t = 0; t < T_; t++) {
    float* hA = h_dec + (t & 1) * 65536;        // old states (read)
    float* hB = h_dec + ((t + 1) & 1) * 65536;  // new states (write)
    float* cA = c_dec + (t & 1) * 65536;
    float* cB = c_dec + ((t + 1) & 1) * 65536;
    // layer 0: [e_t, h_tilde] @ Wih^T + h0 @ Whh^T
    lstm_gates_cell<<<1024, 256, 0, stream>>>(
        emb_t + (size_t)t * B_ * E_, dec0_Wih, 2048, 1024,
        h_til, dec0_Wih + 1024, 2048, 1024,
        hA, dec0_Whh, 1024, 1024,
        dec0_bih, dec0_bhh,
        cA, hB, cB, 1024, 16);
    for (int i = 0; i < 3; i++) {
      lstm_gates_cell<<<1024, 256, 0, stream>>>(
          hB + i * 16384, dec_Wih + (size_t)i * 4096 * 1024, 1024, 1024,
          (const float*)nullptr, (const float*)nullptr, 0, 0,
          hA + (i + 1) * 16384, dec_Whh + (size_t)i * 4096 * 1024, 1024, 1024,
          dec_bih + i * 4096, dec_bhh + i * 4096,
          cA + (i + 1) * 16384, hB + (i + 1) * 16384, cB + (i + 1) * 16384, 1024, 16);
    }
    // attention
    skinny_nt<<<1024, 256, 0, stream>>>(
        hB + 3 * 16384, W_attn, 1024, 1024,
        (const float*)nullptr, (const float*)nullptr, 0, 0,
        (const float*)nullptr, q_buf, (float*)nullptr, 1024, 16, 0);
    attn_ctx<<<16, 256, 0, stream>>>(q_buf, hsrc, ctxb, S_, B_);
    // h_tilde = tanh([h3, ctx] @ W_concat^T + b_concat); also store into h_tilde_seq[t]
    skinny_nt<<<1024, 256, 0, stream>>>(
        hB + 3 * 16384, W_concat, 2048, 1024,
        ctxb, W_concat + 1024, 2048, 1024,
        b_concat, h_til, hts + (size_t)t * B_ * H_, 1024, 16, 1);
  }

  // ================= Generator =================
  dim3 go(V_ / 128, (800 + 127) / 128);
  gemm_nt<<<go, 256, 0, stream>>>(hts, W_out, b_out, (const float*)nullptr,
                                  out, 800, V_, 1024, B_, T_);
  log_softmax_rows<<<800, 256, 0, stream>>>(out, V_);

  (void)in_sizes; (void)n_in; (void)out_size; (void)ws_size;
}